// Round 12
// baseline (23206.062 us; speedup 1.0000x reference)
//
#include <hip/hip_runtime.h>
#include <stdint.h>

#define NN 1000
#define NP 1024
#define TPB 256            // 4 waves; thread tid owns rows 4*tid .. 4*tid+3
#define TT 16384           // LDS-staged input length
#define ZPAD (1008 << 11)  // byte offset of an all-zero padding column

typedef unsigned int u32;
typedef unsigned long long u64;
typedef _Float16 half2v __attribute__((ext_vector_type(2)));
typedef float f32x4 __attribute__((ext_vector_type(4)));   // clang-native for nontemporal

// S[NN][NN] row-major fp32 -> ST16[j][i] fp16, column j contiguous over padded
// row i (stride 1024 halves = 2KB = j<<11 bytes). ALL NP columns written; cols
// >= NN are zero so they serve as no-op padding targets for the gather.
__global__ void transpose_S_f16(const float* __restrict__ S, _Float16* __restrict__ ST) {
    int idx = blockIdx.x * blockDim.x + threadIdx.x;   // 0 .. NP*NP-1
    int j = idx >> 10;          // column 0..1023
    int i = idx & (NP - 1);     // row 0..1023
    float val = (i < NN && j < NN) ? S[i * NN + j] : 0.0f;
    ST[(j << 10) + i] = (_Float16)val;   // RTE
}

__device__ __forceinline__ void acc_pair(u32 p, float& A0, float& A1) {
#if __has_builtin(__builtin_amdgcn_fdot2)
    union { u32 u; half2v h; } cv; cv.u = p;
    const half2v E0 = {(_Float16)1.0f, (_Float16)0.0f};
    const half2v E1 = {(_Float16)0.0f, (_Float16)1.0f};
    A0 = __builtin_amdgcn_fdot2(cv.h, E0, A0, false);
    A1 = __builtin_amdgcn_fdot2(cv.h, E1, A1, false);
#else
    union { u32 u; _Float16 h[2]; } cv; cv.u = p;
    A0 += (float)cv.h[0];
    A1 += (float)cv.h[1];
#endif
}

__global__ void __launch_bounds__(TPB) izhikevich_sim(
    const float* __restrict__ data, const float* __restrict__ U,
    const _Float16* __restrict__ ST,
    const float* __restrict__ a, const float* __restrict__ b,
    const float* __restrict__ c, const float* __restrict__ d,
    const float* __restrict__ v0, const float* __restrict__ u0,
    float* __restrict__ out_states, float* __restrict__ out_v,
    float* __restrict__ out_u, float* __restrict__ out_fir, int T)
{
    __shared__ float sdata[TT];                 // input currents staged once (64 KB)
    __shared__ u64 wmb[4][4];                   // [X][wave]: fired mask of rows 4*thread+X
    __shared__ alignas(8) int fidx[NP + 8];     // fired-column BYTE offsets + 7 pads
    __shared__ int sK;                          // raw fired count

    const int tid  = threadIdx.x;
    const int w    = tid >> 6;
    const int lane = tid & 63;
    const int r0   = tid << 2;                  // first of this thread's 4 rows
    const bool act = (tid < 250);               // rows r0..r0+3 all < 1000
    const int tid8 = tid << 3;                  // byte offset of this thread's uint2 in a column

    // stage data[] into LDS (vectorized, one time)
    {
        const int nv = T >> 2;
        const float4* d4 = (const float4*)data;
        float4* s4 = (float4*)sdata;
        for (int n = tid; n < nv && (n << 2) < TT; n += TPB) s4[n] = d4[n];
        for (int n = (nv << 2) + tid; n < T && n < TT; n += TPB) sdata[n] = data[n];
    }

    float v0r = 0.f, v1r = 0.f, v2r = 0.f, v3r = 0.f;
    float u0r = 0.f, u1r = 0.f, u2r = 0.f, u3r = 0.f;
    float a0 = 0.f, a1 = 0.f, a2 = 0.f, a3 = 0.f;
    float b0 = 0.f, b1 = 0.f, b2 = 0.f, b3 = 0.f;
    float c0 = 0.f, c1 = 0.f, c2 = 0.f, c3 = 0.f;
    float d0 = 0.f, d1 = 0.f, d2 = 0.f, d3 = 0.f;
    float U0 = 0.f, U1 = 0.f, U2 = 0.f, U3 = 0.f;
    if (act) {
        float4 t4;
        t4 = *(const float4*)&v0[r0]; v0r = t4.x; v1r = t4.y; v2r = t4.z; v3r = t4.w;
        t4 = *(const float4*)&u0[r0]; u0r = t4.x; u1r = t4.y; u2r = t4.z; u3r = t4.w;
        t4 = *(const float4*)&a[r0];  a0 = t4.x;  a1 = t4.y;  a2 = t4.z;  a3 = t4.w;
        t4 = *(const float4*)&b[r0];  b0 = t4.x;  b1 = t4.y;  b2 = t4.z;  b3 = t4.w;
        t4 = *(const float4*)&c[r0];  c0 = t4.x;  c1 = t4.y;  c2 = t4.z;  c3 = t4.w;
        t4 = *(const float4*)&d[r0];  d0 = t4.x;  d1 = t4.y;  d2 = t4.z;  d3 = t4.w;
        t4 = *(const float4*)&U[r0];  U0 = t4.x;  U1 = t4.y;  U2 = t4.z;  U3 = t4.w;
    }
    __syncthreads();   // sdata ready

    const char* __restrict__ STb = (const char*)ST;

    for (int t = 0; t < T; ++t) {
        // --- fired masks at start of step t (4 ballots: row class X = 0..3) ---
        const bool f0 = act && (v0r >= 30.0f);
        const bool f1 = act && (v1r >= 30.0f);
        const bool f2 = act && (v2r >= 30.0f);
        const bool f3 = act && (v3r >= 30.0f);
        const u64 bal0 = __ballot(f0);
        const u64 bal1 = __ballot(f1);
        const u64 bal2 = __ballot(f2);
        const u64 bal3 = __ballot(f3);
        if (lane == 0) {
            wmb[0][w] = bal0; wmb[1][w] = bal1; wmb[2][w] = bal2; wmb[3][w] = bal3;
        }
        // reference applies reset twice: v=c (idempotent), u += 2*d
        if (f0) { v0r = c0; u0r += 2.0f * d0; }
        if (f1) { v1r = c1; u1r += 2.0f * d1; }
        if (f2) { v2r = c2; u2r += 2.0f * d2; }
        if (f3) { v3r = c3; u3r += 2.0f * d3; }
        __syncthreads();                          // barrier 1: masks ready

        // --- decode on wave 0: lanes 0..15 expand masks, flat compaction ---
        // lane L -> word (X = L>>2, wv = L&3); bit b -> row 256*(L&3) + 4*b + (L>>2)
        if (w == 0) {
            u64 m = 0; int pc = 0, incl = 0;
            if (lane < 16) {
                m = wmb[lane >> 2][lane & 3];
                pc = __popcll(m);
                incl = pc;
                #pragma unroll
                for (int off = 1; off < 16; off <<= 1) {
                    int o = __shfl_up(incl, off);
                    if (lane >= off) incl += o;
                }
            }
            const int K = __shfl(incl, 15);       // total fired, all lanes
            if (lane >= 16 && lane < 23) fidx[K + (lane - 16)] = ZPAD;  // 7 pads
            if (lane == 23) sK = K;
            if (lane < 16) {
                int base = incl - pc;
                const int rb = (((lane & 3) << 8) + (lane >> 2)) << 11;  // row-base bytes
                while (m) {
                    int bit = __builtin_ctzll(m); m &= m - 1;
                    fidx[base++] = rb + (bit << 13);   // (row + 4*bit) << 11
                }
            }
        }
        __syncthreads();                          // barrier 2: fidx/sK ready

        // --- gather: uint2 per lane (8B = 4 rows), unroll 8, two acc quads ---
        const float xt = sdata[t];
        float I0 = xt * U0, I1 = xt * U1, I2 = xt * U2, I3 = xt * U3;
        float J0 = 0.0f, J1 = 0.0f, J2 = 0.0f, J3 = 0.0f;
        const int K = sK;
        for (int n = 0; n < K; n += 8) {
            const int2 oa = *(const int2*)&fidx[n + 0];
            const int2 ob = *(const int2*)&fidx[n + 2];
            const int2 oc = *(const int2*)&fidx[n + 4];
            const int2 od = *(const int2*)&fidx[n + 6];
            const uint2 q0 = *(const uint2*)(STb + oa.x + tid8);
            const uint2 q1 = *(const uint2*)(STb + oa.y + tid8);
            const uint2 q2 = *(const uint2*)(STb + ob.x + tid8);
            const uint2 q3 = *(const uint2*)(STb + ob.y + tid8);
            const uint2 q4 = *(const uint2*)(STb + oc.x + tid8);
            const uint2 q5 = *(const uint2*)(STb + oc.y + tid8);
            const uint2 q6 = *(const uint2*)(STb + od.x + tid8);
            const uint2 q7 = *(const uint2*)(STb + od.y + tid8);
            acc_pair(q0.x, I0, I1); acc_pair(q0.y, I2, I3);
            acc_pair(q1.x, J0, J1); acc_pair(q1.y, J2, J3);
            acc_pair(q2.x, I0, I1); acc_pair(q2.y, I2, I3);
            acc_pair(q3.x, J0, J1); acc_pair(q3.y, J2, J3);
            acc_pair(q4.x, I0, I1); acc_pair(q4.y, I2, I3);
            acc_pair(q5.x, J0, J1); acc_pair(q5.y, J2, J3);
            acc_pair(q6.x, I0, I1); acc_pair(q6.y, I2, I3);
            acc_pair(q7.x, J0, J1); acc_pair(q7.y, J2, J3);
        }
        I0 += J0; I1 += J1; I2 += J2; I3 += J3;

        // --- update + outputs ---
        if (act) {
            v0r = v0r + 0.5f * (0.04f * v0r * v0r + 5.0f * v0r + 140.0f - u0r + I0);
            u0r = u0r + a0 * (b0 * v0r - u0r);
            v1r = v1r + 0.5f * (0.04f * v1r * v1r + 5.0f * v1r + 140.0f - u1r + I1);
            u1r = u1r + a1 * (b1 * v1r - u1r);
            v2r = v2r + 0.5f * (0.04f * v2r * v2r + 5.0f * v2r + 140.0f - u2r + I2);
            u2r = u2r + a2 * (b2 * v2r - u2r);
            v3r = v3r + 0.5f * (0.04f * v3r * v3r + 5.0f * v3r + 140.0f - u3r + I3);
            u3r = u3r + a3 * (b3 * v3r - u3r);
            f32x4 st, fr;
            st.x = (v0r >= 30.0f) ? 1.0f : 0.0f;
            st.y = (v1r >= 30.0f) ? 1.0f : 0.0f;
            st.z = (v2r >= 30.0f) ? 1.0f : 0.0f;
            st.w = (v3r >= 30.0f) ? 1.0f : 0.0f;
            fr.x = f0 ? 1.0f : 0.0f;
            fr.y = f1 ? 1.0f : 0.0f;
            fr.z = f2 ? 1.0f : 0.0f;
            fr.w = f3 ? 1.0f : 0.0f;
            __builtin_nontemporal_store(st, (f32x4*)&out_states[(size_t)t * NN + r0]);
            __builtin_nontemporal_store(fr, (f32x4*)&out_fir[(size_t)t * NN + r0]);
        }
        // hazards: wmb is re-written at t+1 only after B2(t) (readers finished
        // decode(t) before their B2(t)); fidx re-written at t+1 only after
        // B1(t+1), by which point all gather reads of step t completed.
    }

    if (act) {
        float4 vv, uu;
        vv.x = v0r; vv.y = v1r; vv.z = v2r; vv.w = v3r;
        uu.x = u0r; uu.y = u1r; uu.z = u2r; uu.w = u3r;
        *(float4*)&out_v[r0] = vv;
        *(float4*)&out_u[r0] = uu;
    }
}

extern "C" void kernel_launch(void* const* d_in, const int* in_sizes, int n_in,
                              void* d_out, int out_size, void* d_ws, size_t ws_size,
                              hipStream_t stream) {
    const float* data = (const float*)d_in[0];
    const float* U    = (const float*)d_in[1];
    const float* S    = (const float*)d_in[2];
    const float* a    = (const float*)d_in[3];
    const float* b    = (const float*)d_in[4];
    const float* c    = (const float*)d_in[5];
    const float* dd   = (const float*)d_in[6];
    const float* v0   = (const float*)d_in[7];
    const float* u0   = (const float*)d_in[8];
    const int T = in_sizes[0];   // 16384

    _Float16* ST = (_Float16*)d_ws;   // NP*NP halves = 2 MB

    float* out        = (float*)d_out;
    float* out_states = out;                          // [T, NN]
    float* out_v      = out + (size_t)T * NN;         // [NN]
    float* out_u      = out_v + NN;                   // [NN]
    float* out_fir    = out_u + NN;                   // [T, NN]

    hipLaunchKernelGGL(transpose_S_f16, dim3((NP * NP) / 256), dim3(256), 0, stream, S, ST);
    hipLaunchKernelGGL(izhikevich_sim, dim3(1), dim3(TPB), 0, stream,
                       data, U, ST, a, b, c, dd, v0, u0,
                       out_states, out_v, out_u, out_fir, T);
}

// Round 13
// 19824.562 us; speedup vs baseline: 1.1706x; 1.1706x over previous
//
#include <hip/hip_runtime.h>
#include <stdint.h>

#define NN 1000
#define NP 1024
#define TPB 512          // 8 waves; thread tid owns rows 2*tid and 2*tid+1
#define TT 16384         // LDS-staged input length

typedef unsigned int u32;
typedef unsigned long long u64;
typedef _Float16 half2v __attribute__((ext_vector_type(2)));

// S[NN][NN] row-major fp32 -> ST16[j][i] fp16, column j contiguous over padded
// row i (stride 1024 halves = 2KB). ALL NP columns written; cols >= NN are zero
// so they can serve as no-op padding targets for the unrolled gather.
__global__ void transpose_S_f16(const float* __restrict__ S, _Float16* __restrict__ ST) {
    int idx = blockIdx.x * blockDim.x + threadIdx.x;   // 0 .. NP*NP-1
    int j = idx >> 10;          // column 0..1023
    int i = idx & (NP - 1);     // row 0..1023
    float val = (i < NN && j < NN) ? S[i * NN + j] : 0.0f;
    ST[(j << 10) + i] = (_Float16)val;   // RTE
}

__device__ __forceinline__ void acc_pair(u32 p, float& A0, float& A1) {
#if __has_builtin(__builtin_amdgcn_fdot2)
    union { u32 u; half2v h; } cv; cv.u = p;
    const half2v E0 = {(_Float16)1.0f, (_Float16)0.0f};
    const half2v E1 = {(_Float16)0.0f, (_Float16)1.0f};
    A0 = __builtin_amdgcn_fdot2(cv.h, E0, A0, false);
    A1 = __builtin_amdgcn_fdot2(cv.h, E1, A1, false);
#else
    union { u32 u; _Float16 h[2]; } cv; cv.u = p;
    A0 += (float)cv.h[0];
    A1 += (float)cv.h[1];
#endif
}

__global__ void __launch_bounds__(TPB) izhikevich_sim(
    const float* __restrict__ data, const float* __restrict__ U,
    const _Float16* __restrict__ ST,
    const float* __restrict__ a, const float* __restrict__ b,
    const float* __restrict__ c, const float* __restrict__ d,
    const float* __restrict__ v0, const float* __restrict__ u0,
    float* __restrict__ out_states, float* __restrict__ out_v,
    float* __restrict__ out_u, float* __restrict__ out_fir, int T)
{
    __shared__ float sdata[TT];        // input currents staged once
    __shared__ u64 wm0[8];             // fired mask, even rows of wave w's span
    __shared__ u64 wm1[8];             // odd rows
    __shared__ int fidx[NP + 8];       // flat fired-column list + unroll pad
    __shared__ int sKtot;

    const int tid  = threadIdx.x;
    const int w    = tid >> 6;
    const int lane = tid & 63;
    const int r0   = tid << 1;
    const bool act = (r0 < NN);

    // stage data[] into LDS (vectorized, one time)
    {
        const int nv = T >> 2;
        const float4* d4 = (const float4*)data;
        float4* s4 = (float4*)sdata;
        for (int n = tid; n < nv && (n << 2) < TT; n += TPB) s4[n] = d4[n];
        for (int n = (nv << 2) + tid; n < T && n < TT; n += TPB) sdata[n] = data[n];
    }

    float v0r = 0.f, v1r = 0.f, u0r = 0.f, u1r = 0.f;
    float a0 = 0.f, a1 = 0.f, b0 = 0.f, b1 = 0.f, c0 = 0.f, c1 = 0.f;
    float d0 = 0.f, d1 = 0.f, U0 = 0.f, U1 = 0.f;
    if (act) {
        float2 t2;
        t2 = *(const float2*)&v0[r0]; v0r = t2.x; v1r = t2.y;
        t2 = *(const float2*)&u0[r0]; u0r = t2.x; u1r = t2.y;
        t2 = *(const float2*)&a[r0];  a0 = t2.x;  a1 = t2.y;
        t2 = *(const float2*)&b[r0];  b0 = t2.x;  b1 = t2.y;
        t2 = *(const float2*)&c[r0];  c0 = t2.x;  c1 = t2.y;
        t2 = *(const float2*)&d[r0];  d0 = t2.x;  d1 = t2.y;
        t2 = *(const float2*)&U[r0];  U0 = t2.x;  U1 = t2.y;
    }
    __syncthreads();   // sdata ready

    const u32* __restrict__ STu = (const u32*)ST;  // u32 [j<<9 + tid] = rows 2tid,2tid+1

    for (int t = 0; t < T; ++t) {
        // --- fired masks at start of step t ---
        const bool f0 = act && (v0r >= 30.0f);
        const bool f1 = act && (v1r >= 30.0f);
        const u64 bal0 = __ballot(f0);
        const u64 bal1 = __ballot(f1);
        if (lane == 0) { wm0[w] = bal0; wm1[w] = bal1; }
        // reference applies reset twice: v=c (idempotent), u += 2*d
        if (f0) { v0r = c0; u0r += 2.0f * d0; }
        if (f1) { v1r = c1; u1r += 2.0f * d1; }
        __syncthreads();                          // barrier 1: masks ready

        // --- decode: 16 lanes of wave 0, one u64 each, flat compaction ---
        if (w == 0 && lane < 16) {
            u64 m = (lane < 8) ? wm0[lane] : wm1[lane - 8];
            const int pc = __popcll(m);
            int incl = pc;
            #pragma unroll
            for (int off = 1; off < 16; off <<= 1) {
                int o = __shfl_up(incl, off);
                if (lane >= off) incl += o;
            }
            int base = incl - pc;
            if (lane == 15) {
                sKtot = incl;
                #pragma unroll
                for (int p = 0; p < 8; ++p) fidx[incl + p] = NN;  // zero column
            }
            const int rowbase = (lane & 7) << 7;
            const int odd = lane >> 3;
            while (m) {
                int bit = __builtin_ctzll(m); m &= m - 1;
                fidx[base++] = rowbase + (bit << 1) + odd;
            }
        }
        __syncthreads();                          // barrier 2: fidx/sKtot ready

        // --- gather: unroll 8, two accumulator pairs for load parallelism ---
        const float xt = (t < TT) ? sdata[t] : data[t];
        float I0 = xt * U0, I1 = xt * U1;
        float J0 = 0.0f, J1 = 0.0f;
        const int ktot = sKtot;
        for (int n = 0; n < ktot; n += 8) {
            const int j0 = fidx[n + 0] << 9;
            const int j1 = fidx[n + 1] << 9;
            const int j2 = fidx[n + 2] << 9;
            const int j3 = fidx[n + 3] << 9;
            const int j4 = fidx[n + 4] << 9;
            const int j5 = fidx[n + 5] << 9;
            const int j6 = fidx[n + 6] << 9;
            const int j7 = fidx[n + 7] << 9;
            const u32 p0 = STu[j0 + tid];
            const u32 p1 = STu[j1 + tid];
            const u32 p2 = STu[j2 + tid];
            const u32 p3 = STu[j3 + tid];
            const u32 p4 = STu[j4 + tid];
            const u32 p5 = STu[j5 + tid];
            const u32 p6 = STu[j6 + tid];
            const u32 p7 = STu[j7 + tid];
            acc_pair(p0, I0, I1); acc_pair(p1, J0, J1);
            acc_pair(p2, I0, I1); acc_pair(p3, J0, J1);
            acc_pair(p4, I0, I1); acc_pair(p5, J0, J1);
            acc_pair(p6, I0, I1); acc_pair(p7, J0, J1);
        }
        I0 += J0; I1 += J1;

        // --- update + outputs ---
        if (act) {
            v0r = v0r + 0.5f * (0.04f * v0r * v0r + 5.0f * v0r + 140.0f - u0r + I0);
            u0r = u0r + a0 * (b0 * v0r - u0r);
            v1r = v1r + 0.5f * (0.04f * v1r * v1r + 5.0f * v1r + 140.0f - u1r + I1);
            u1r = u1r + a1 * (b1 * v1r - u1r);
            union { float2 f; u64 u; } st, fr;
            st.f.x = (v0r >= 30.0f) ? 1.0f : 0.0f;
            st.f.y = (v1r >= 30.0f) ? 1.0f : 0.0f;
            fr.f.x = f0 ? 1.0f : 0.0f;
            fr.f.y = f1 ? 1.0f : 0.0f;
            __builtin_nontemporal_store(st.u, (u64*)&out_states[(size_t)t * NN + r0]);
            __builtin_nontemporal_store(fr.u, (u64*)&out_fir[(size_t)t * NN + r0]);
        }
        // no third barrier: wave entering step t+1's mask-write passed barrier 2
        // of step t (decode(t) done); decode(t+1) happens after barrier 1 of
        // step t+1, by which point all gathers of step t (pre-barrier-1 work)
        // are complete.
    }

    if (act) {
        float2 vv, uu;
        vv.x = v0r; vv.y = v1r;
        uu.x = u0r; uu.y = u1r;
        *(float2*)&out_v[r0] = vv;
        *(float2*)&out_u[r0] = uu;
    }
}

extern "C" void kernel_launch(void* const* d_in, const int* in_sizes, int n_in,
                              void* d_out, int out_size, void* d_ws, size_t ws_size,
                              hipStream_t stream) {
    const float* data = (const float*)d_in[0];
    const float* U    = (const float*)d_in[1];
    const float* S    = (const float*)d_in[2];
    const float* a    = (const float*)d_in[3];
    const float* b    = (const float*)d_in[4];
    const float* c    = (const float*)d_in[5];
    const float* dd   = (const float*)d_in[6];
    const float* v0   = (const float*)d_in[7];
    const float* u0   = (const float*)d_in[8];
    const int T = in_sizes[0];   // 16384

    _Float16* ST = (_Float16*)d_ws;   // NP*NP halves = 2 MB

    float* out        = (float*)d_out;
    float* out_states = out;                          // [T, NN]
    float* out_v      = out + (size_t)T * NN;         // [NN]
    float* out_u      = out_v + NN;                   // [NN]
    float* out_fir    = out_u + NN;                   // [T, NN]

    hipLaunchKernelGGL(transpose_S_f16, dim3((NP * NP) / 256), dim3(256), 0, stream, S, ST);
    hipLaunchKernelGGL(izhikevich_sim, dim3(1), dim3(TPB), 0, stream,
                       data, U, ST, a, b, c, dd, v0, u0,
                       out_states, out_v, out_u, out_fir, T);
}